// Round 8
// baseline (377.757 us; speedup 1.0000x reference)
//
#include <hip/hip_runtime.h>
#include <hip/hip_bf16.h>

// GNNLayer fused — round 8: resubmit of the round-6 VALU-overhead cut
// (rounds 6 and 7 both died on GPU acquisition; kernel never ran; three
// audits clean — incl. cross-phase LDS race audit this round).
// R5 measured: 145us kernel, MfmaUtil 9.0, VALUBusy 37.5, conflicts 8.8e6.
// Changes vs R5: (1) hoisted per-lane LDS offsets ((row&7)==(dl&7) identity) so
// B/A-frag reads are base+imm; (2) store_cd offsets via disjoint-bit XOR
// decomposition + v_cvt_pk bf16 conversions; (3) fp32 v-staging epilogue with
// coalesced float4 residual re-read + dwordx4 scatter + 2-shuffle LN reduce;
// (4) pack_weights coalesced, 96 blocks.

#define BB 16
#define NN 10000
#define DD 128
#define TT 62
#define NTHREADS 256
#define EPS_LN 1e-5f

typedef __attribute__((ext_vector_type(8))) short short8v;
typedef __attribute__((ext_vector_type(4))) float f32x4;

__device__ __forceinline__ unsigned short cvt_bf16(float f) {
    __hip_bfloat16 h = __float2bfloat16(f);
    union { __hip_bfloat16 h; unsigned short u; } cv; cv.h = h; return cv.u;
}
__device__ __forceinline__ unsigned cvt2_bf16(float a, float b) {
    __hip_bfloat162 h2 = __float22bfloat162_rn(make_float2(a, b));
    union { __hip_bfloat162 h; unsigned u; } cv; cv.h = h2; return cv.u;
}
__device__ __forceinline__ float bf16f(unsigned short h) {
    union { unsigned u; float f; } v; v.u = ((unsigned)h) << 16;
    return v.f;
}
__device__ __forceinline__ float silu_f(float x) { return x / (1.0f + __expf(-x)); }

__device__ __forceinline__ int tour_at(const int* tw, bool is64, long long i) {
    int v = is64 ? (int)(((const long long*)tw)[i]) : tw[i];
    return (v < 0 || v >= NN) ? 0 : v;
}

// byte offset of bf16 element k within a swizzled 256B row
__device__ __forceinline__ int swz(int row, int k) {
    return (((k >> 3) ^ (row & 7)) << 4) | ((k & 7) << 1);
}

// ---------------- weight pack (coalesced) ----------------
// images [n=0..127][k=0..127] bf16, 32KB each, swizzle baked:
// 0:W1b=W1m[128+k][n] 1:W1a=W1m[k][n] 2:W2m 3:W1u_x 4:W1u_m=W1u[128+k][n] 5:W2u
__global__ void pack_weights(const float* __restrict__ W1m, const float* __restrict__ W2m,
                             const float* __restrict__ W1u, const float* __restrict__ W2u,
                             unsigned short* __restrict__ wp)
{
    int t = blockIdx.x * blockDim.x + threadIdx.x;   // 24576 threads
    int img = t >> 12;
    int r   = t & 4095;
    int k   = r >> 5;          // 0..127
    int n4  = (r & 31) * 4;    // 0..124
    const float* src; int koff;
    switch (img) {
      case 0: src = W1m; koff = 128; break;
      case 1: src = W1m; koff = 0;   break;
      case 2: src = W2m; koff = 0;   break;
      case 3: src = W1u; koff = 0;   break;
      case 4: src = W1u; koff = 128; break;
      default: src = W2u; koff = 0;  break;
    }
    const float4 v = *(const float4*)(src + (koff + k) * 128 + n4);   // coalesced in n
    const float vs[4] = {v.x, v.y, v.z, v.w};
    const int g = k >> 3, klo = (k & 7) * 2;
    #pragma unroll
    for (int i = 0; i < 4; ++i) {
        int n = n4 + i;
        *(unsigned short*)((char*)wp + img * 32768 + n * 256 + ((g ^ (n & 7)) << 4) + klo)
            = cvt_bf16(vs[i]);
    }
}

// ---------------- main kernel ----------------
__global__ __launch_bounds__(NTHREADS, 2)
void gnn_mfma_kernel(const float* __restrict__ h, const int* __restrict__ tour_raw,
                     const unsigned short* __restrict__ wp,
                     const float* __restrict__ b1m, const float* __restrict__ b2m,
                     const float* __restrict__ b1u, const float* __restrict__ b2u,
                     const float* __restrict__ gma, const float* __restrict__ bta,
                     float* __restrict__ out)
{
    __shared__ unsigned char lds[81920];        // 80KB -> 2 blocks/CU
    unsigned char* XA = lds;                    // x   bf16 [64][128] swizzled
    unsigned char* CB = lds + 16384;            // c   bf16
    unsigned char* SB = lds + 32768;            // s/msg/z bf16 (reused)
    unsigned char* WS = lds + 49152;            // weight slot (32KB)
    float* VS = (float*)(lds + 16384);          // phase-5 fp32 v-stage (32KB = CB+SB)

    const int tid  = threadIdx.x;
    const int b    = blockIdx.y;
    const int t0   = blockIdx.x * TT;
    const int Tl   = min(TT, NN - t0);
    const int lane = tid & 63;
    const int w    = tid >> 6;
    const int dl   = lane & 15;
    const int lg   = lane >> 4;

    const bool is64 = (tour_raw[1] == 0) && (tour_raw[3] == 0);
    const long long tbase = (long long)b * NN;
    const float* hb = h + (long long)b * NN * DD;

    // biases needed in GEMM epilogues, per-lane dim(nt) = nt*16 + dl
    float vb1m[8], vb2m_2[8], vb1u[8];
    #pragma unroll
    for (int nt = 0; nt < 8; ++nt) {
        int d = nt * 16 + dl;
        vb1m[nt] = b1m[d]; vb2m_2[nt] = 2.0f * b2m[d]; vb1u[nt] = b1u[d];
    }

    // hoisted per-lane fragment offsets: (w*16+dl)&7 == dl&7
    int ofsB[4], ofsA[4];
    #pragma unroll
    for (int ks = 0; ks < 4; ++ks) {
        ofsB[ks] = dl * 256 + (((ks * 4 + lg) ^ (dl & 7)) << 4);
        ofsA[ks] = ofsB[ks] + w * 4096;
    }
    const unsigned char* pB[4] = {WS + ofsB[0], WS + ofsB[1], WS + ofsB[2], WS + ofsB[3]};

    // ---- gather x -> XA. rows 0..61 main, 62 prev-halo, 63 next-halo
    #pragma unroll
    for (int p = 0; p < 4; ++p) {
        int id  = tid + p * NTHREADS;   // 64 rows x 16 granules
        int row = id >> 4;
        int gg  = id & 15;
        int gi;
        if (row < TT)       gi = (row < Tl) ? (t0 + row) : t0;
        else if (row == TT) gi = (t0 == 0) ? (NN - 1) : (t0 - 1);
        else                gi = (t0 + Tl >= NN) ? 0 : (t0 + Tl);
        int node = tour_at(tour_raw, is64, tbase + gi);
        const float4 f0 = *(const float4*)(hb + node * DD + gg * 8);
        const float4 f1 = *(const float4*)(hb + node * DD + gg * 8 + 4);
        uint4 vv;
        vv.x = cvt2_bf16(f0.x, f0.y); vv.y = cvt2_bf16(f0.z, f0.w);
        vv.z = cvt2_bf16(f1.x, f1.y); vv.w = cvt2_bf16(f1.z, f1.w);
        *(uint4*)(XA + row * 256 + ((gg ^ (row & 7)) << 4)) = vv;
    }

    f32x4 acc[8], acc_a[8], acc_z[8];
    short8v afr[4];
    uint4 wfull[8];

    auto wload8 = [&](int img) {
        #pragma unroll
        for (int r = 0; r < 8; ++r)
            wfull[r] = *(const uint4*)((const char*)wp + img * 32768 + r * 4096 + tid * 16);
    };
    auto wstore8 = [&]() {
        #pragma unroll
        for (int r = 0; r < 8; ++r)
            *(uint4*)(WS + r * 4096 + tid * 16) = wfull[r];
    };
    auto load_afrag = [&](int pofs) {
        #pragma unroll
        for (int ks = 0; ks < 4; ++ks)
            afr[ks] = *(const short8v*)(lds + pofs + ofsA[ks]);
    };
    auto zero8 = [&](f32x4* A) {
        #pragma unroll
        for (int nt = 0; nt < 8; ++nt) A[nt] = (f32x4){0.f, 0.f, 0.f, 0.f};
    };
    auto gemm_acc = [&](f32x4* A) {
        #pragma unroll
        for (int ks = 0; ks < 4; ++ks) {
            #pragma unroll
            for (int nt = 0; nt < 8; ++nt) {
                short8v bf = *(const short8v*)(pB[ks] + nt * 4096);
                A[nt] = __builtin_amdgcn_mfma_f32_16x16x32_bf16(afr[ks], bf, A[nt], 0, 0, 0);
            }
        }
    };
    // store C/D (row=(l>>4)*4+reg, col=l&15) as bf16 into swizzled act layout.
    // addr = row*256 + (dl&7)*2 + (b0<<4) + ((nt<<5)^crs)  [disjoint-bit split]
    auto store_cd = [&](unsigned char* P, f32x4* A) {
        #pragma unroll
        for (int reg = 0; reg < 4; ++reg) {
            int row = w * 16 + lg * 4 + reg;
            int b0  = ((dl >> 3) ^ row) & 1;
            int crs = (((row & 7) >> 1)) << 5;
            unsigned char* base = P + row * 256 + (b0 << 4) + ((dl & 7) << 1);
            #pragma unroll
            for (int nt = 0; nt < 8; ++nt)
                *(unsigned short*)(base + ((nt << 5) ^ crs)) = cvt_bf16(A[nt][reg]);
        }
    };

    // ================= phases =================
    wload8(0);

    // phase 0: c = x @ W1b (halo rows included)
    __syncthreads();
    wstore8(); wload8(1);
    load_afrag(0);                 // XA
    zero8(acc);
    __syncthreads();
    gemm_acc(acc);
    store_cd(CB, acc);

    // phase 1: a = x @ W1a ; s = silu(a+c_prev+b1m)+silu(a+c_next+b1m)
    __syncthreads();
    wstore8(); wload8(2);
    zero8(acc_a);                  // afr still = x
    __syncthreads();
    gemm_acc(acc_a);
    #pragma unroll
    for (int nt = 0; nt < 8; ++nt) {
        int d = nt * 16 + dl;
        #pragma unroll
        for (int reg = 0; reg < 4; ++reg) {
            int row = w * 16 + lg * 4 + reg;
            int jp = (row == 0) ? 62 : row - 1;
            int jn = (row >= Tl - 1) ? 63 : row + 1;
            float aij = acc_a[nt][reg] + vb1m[nt];
            float cp = bf16f(*(const unsigned short*)(CB + jp * 256 + swz(jp, d)));
            float cn = bf16f(*(const unsigned short*)(CB + jn * 256 + swz(jn, d)));
            acc_a[nt][reg] = silu_f(aij + cp) + silu_f(aij + cn);
        }
    }
    store_cd(SB, acc_a);           // SB = s

    // phase 2: msg = s @ W2m + 2*b2m
    __syncthreads();
    wstore8(); wload8(3);
    load_afrag(32768);             // SB
    zero8(acc);
    __syncthreads();
    gemm_acc(acc);
    #pragma unroll
    for (int nt = 0; nt < 8; ++nt)
        #pragma unroll
        for (int reg = 0; reg < 4; ++reg) acc[nt][reg] += vb2m_2[nt];
    store_cd(SB, acc);             // SB = msg

    // phase 3: z = x @ W1u_x
    __syncthreads();
    wstore8(); wload8(4);
    load_afrag(0);                 // XA
    zero8(acc_z);
    __syncthreads();
    gemm_acc(acc_z);

    // phase 4: z += msg @ W1u_m ; z = silu(z + b1u)
    __syncthreads();
    wstore8(); wload8(5);
    load_afrag(32768);             // SB = msg
    __syncthreads();
    gemm_acc(acc_z);
    #pragma unroll
    for (int nt = 0; nt < 8; ++nt)
        #pragma unroll
        for (int reg = 0; reg < 4; ++reg)
            acc_z[nt][reg] = silu_f(acc_z[nt][reg] + vb1u[nt]);
    store_cd(SB, acc_z);           // SB = z

    // phase 5: v = z @ W2u ; stage v fp32; LN(x+v+b2u) ; scatter
    __syncthreads();
    wstore8();
    load_afrag(32768);             // SB = z
    zero8(acc);
    __syncthreads();
    gemm_acc(acc);

    // fp32 v-stage into VS (64 rows x 128 dwords, slot-swizzled)
    #pragma unroll
    for (int nt = 0; nt < 8; ++nt) {
        #pragma unroll
        for (int reg = 0; reg < 4; ++reg) {
            int row = w * 16 + lg * 4 + reg;
            VS[row * 128 + ((nt ^ (row & 7)) << 4) + dl] = acc[nt][reg];
        }
    }
    __syncthreads();

    // thread t: row = t>>2, dims [ (t&3)*32 , +32 )
    {
        const int row = tid >> 2;
        const int d0  = (tid & 3) * 32;
        const bool valid = row < Tl;
        const int node = tour_at(tour_raw, is64, tbase + t0 + (valid ? row : 0));
        const float* xg = hb + node * DD + d0;
        const int r7 = row & 7;
        f32x4 r[8];
        float s1 = 0.f, s2 = 0.f;
        #pragma unroll
        for (int c = 0; c < 8; ++c) {
            const int d = d0 + c * 4;
            const f32x4 v = *(const f32x4*)&VS[row * 128 + (((d >> 4) ^ r7) << 4) + (d & 15)];
            const float4 x = *(const float4*)(xg + c * 4);
            const float4 bb = *(const float4*)(b2u + d);
            r[c][0] = x.x + v[0] + bb.x;
            r[c][1] = x.y + v[1] + bb.y;
            r[c][2] = x.z + v[2] + bb.z;
            r[c][3] = x.w + v[3] + bb.w;
            #pragma unroll
            for (int j = 0; j < 4; ++j) { s1 += r[c][j]; s2 += r[c][j] * r[c][j]; }
        }
        s1 += __shfl_xor(s1, 1, 64); s2 += __shfl_xor(s2, 1, 64);
        s1 += __shfl_xor(s1, 2, 64); s2 += __shfl_xor(s2, 2, 64);
        const float mu  = s1 * (1.0f / 128.0f);
        const float var = s2 * (1.0f / 128.0f) - mu * mu;
        const float rs  = rsqrtf(var + EPS_LN);
        if (valid) {
            float* op = out + ((long long)b * NN + node) * DD + d0;
            #pragma unroll
            for (int c = 0; c < 8; ++c) {
                const int d = d0 + c * 4;
                const float4 g4 = *(const float4*)(gma + d);
                const float4 t4 = *(const float4*)(bta + d);
                float4 o;
                o.x = (r[c][0] - mu) * rs * g4.x + t4.x;
                o.y = (r[c][1] - mu) * rs * g4.y + t4.y;
                o.z = (r[c][2] - mu) * rs * g4.z + t4.z;
                o.w = (r[c][3] - mu) * rs * g4.w + t4.w;
                *(float4*)(op + c * 4) = o;
            }
        }
    }
}

extern "C" void kernel_launch(void* const* d_in, const int* in_sizes, int n_in,
                              void* d_out, int out_size, void* d_ws, size_t ws_size,
                              hipStream_t stream)
{
    const float* h    = (const float*)d_in[0];
    const int*   tour = (const int*)d_in[1];
    const float* W1m  = (const float*)d_in[2];
    const float* b1m  = (const float*)d_in[3];
    const float* W2m  = (const float*)d_in[4];
    const float* b2m  = (const float*)d_in[5];
    const float* W1u  = (const float*)d_in[6];
    const float* b1u  = (const float*)d_in[7];
    const float* W2u  = (const float*)d_in[8];
    const float* b2u  = (const float*)d_in[9];
    const float* gma  = (const float*)d_in[10];
    const float* bta  = (const float*)d_in[11];
    float*       out  = (float*)d_out;
    unsigned short* wp = (unsigned short*)d_ws;     // 6*32KB packed weights

    pack_weights<<<96, NTHREADS, 0, stream>>>(W1m, W2m, W1u, W2u, wp);

    dim3 grid((NN + TT - 1) / TT, BB);
    gnn_mfma_kernel<<<grid, NTHREADS, 0, stream>>>(h, tour, wp, b1m, b2m, b1u, b2u,
                                                   gma, bta, out);
}